// Round 4
// baseline (987.609 us; speedup 1.0000x reference)
//
#include <hip/hip_runtime.h>
#include <hip/hip_cooperative_groups.h>
#include <cstdio>

namespace cg = cooperative_groups;

// CapsuleLayer dynamic routing, MI355X (gfx950). Round 4.
// Key facts: W = 67 MB, x = 8.4 MB -> whole problem is L3-resident; HBM floor
// ~12 us. Round-3's 186 us was launch-chain + staging overhead, not BW.
// Design: ONE cooperative kernel, 256 blocks (1/CU) x 512 thr (8 waves).
//  - Block stages its 8-capsule W slice ONCE into LDS as bf16 MFMA A-frags
//    (128 KB) + x B-frags (16 KB); reused across all 3 routing passes.
//  - Waves 0-3 = batch-group 0, waves 4-7 = bg 1; wave owns 4 mt-tiles.
//  - Per-pass cross-block reduction via part[bg][jd][icq][b][ic_lo] fp16 in
//    ws (L3), grid.sync(), 64 blocks reduce+squash+update ST, grid.sync().
//  - Softmax: no max-subtract (logits bounded), per-wave partial Z through
//    LDS, one block barrier per i-iteration (parity double-buffered).

#define IPB   8
#define NBLK  256
#define JDIM  512
#define EPS_SQ 1e-7f

typedef short    s16x4  __attribute__((ext_vector_type(4)));
typedef short    s16x8  __attribute__((ext_vector_type(8)));
typedef float    f32x16 __attribute__((ext_vector_type(16)));
typedef _Float16 h16x8  __attribute__((ext_vector_type(8)));
typedef unsigned u32;

// LDS layout in u32 units
#define WF_OFF 0                    // wfrag [8 i][16 mt][64 l][4]  = 131072 B
#define XF_OFF 32768                // xfrag [8 i][2 bg][64 l][4]  =  16384 B
#define ZB_OFF 36864                // zbuf  [2][8 w][33] float    =   2112 B
#define SL_OFF (ZB_OFF + 528)       // sl    [16][33] float        =   2112 B
#define LDS_U32 (SL_OFF + 528)
#define LDS_BYTES (LDS_U32 * 4)     // 151,680 B (< 160 KiB)

__device__ inline short bfc(float f) {
  u32 u = __builtin_bit_cast(u32, f);
  u32 r = (u + 0x7FFFu + ((u >> 16) & 1u)) >> 16;
  return (short)(unsigned short)r;
}
__device__ inline u32 pk2(float a, float b) {
  return (u32)(unsigned short)bfc(a) | ((u32)(unsigned short)bfc(b) << 16);
}
__device__ inline float sum8(h16x8 v) {
  return (((float)v[0] + (float)v[1]) + ((float)v[2] + (float)v[3])) +
         (((float)v[4] + (float)v[5]) + ((float)v[6] + (float)v[7]));
}

__global__ __launch_bounds__(512, 2) void k_all(const float* __restrict__ W,
                                                const float* __restrict__ x,
                                                float* __restrict__ out,
                                                float* __restrict__ ST,
                                                _Float16* __restrict__ part) {
  extern __shared__ u32 lds[];
  u32*   wfrag = lds + WF_OFF;
  u32*   xfrag = lds + XF_OFF;
  float* zbuf  = (float*)(lds + ZB_OFF);
  float* sl    = (float*)(lds + SL_OFF);

  const int ic  = blockIdx.x;
  const int tid = threadIdx.x;
  const int w   = tid >> 6;
  const int l   = tid & 63;
  const int col = l & 31;
  const int hi  = l >> 5;
  const int bg  = w >> 2;          // waves 0-3: batch 0-31, waves 4-7: 32-63
  const int wm  = w & 3;           // mt = wm*4 + m
  const int i0  = ic * IPB;

  // ---------------- stage W + x into LDS fragments (once) ----------------
  {
    float4 wreg[32];
    const float* wsrc = W + (size_t)i0 * 8192;
#pragma unroll
    for (int ii = 0; ii < IPB; ii++)
#pragma unroll
      for (int q4 = 0; q4 < 4; q4++)
        wreg[ii * 4 + q4] =
            *(const float4*)(wsrc + (size_t)ii * 8192 + (size_t)(q4 * 512 + tid) * 4);

    // x: thread t -> row (b = t>>3, i = i0 + (t&7)), 16 floats contiguous
    const int xb = tid >> 3, xi = tid & 7;
    const float* xsrc = x + ((size_t)xb * 2048 + i0 + xi) * 16;
    float4 xv0 = *(const float4*)(xsrc);
    float4 xv1 = *(const float4*)(xsrc + 4);
    float4 xv2 = *(const float4*)(xsrc + 8);
    float4 xv3 = *(const float4*)(xsrc + 12);
    {
      int lbg = xb >> 5, lc = xb & 31;
      u32* d0 = xfrag + (((size_t)xi * 2 + lbg) * 64 + lc) * 4;       // hi=0
      d0[0] = pk2(xv0.x, xv0.y); d0[1] = pk2(xv0.z, xv0.w);
      d0[2] = pk2(xv2.x, xv2.y); d0[3] = pk2(xv2.z, xv2.w);
      u32* d1 = d0 + 32 * 4;                                          // hi=1
      d1[0] = pk2(xv1.x, xv1.y); d1[1] = pk2(xv1.z, xv1.w);
      d1[2] = pk2(xv3.x, xv3.y); d1[3] = pk2(xv3.z, xv3.w);
    }
#pragma unroll
    for (int ii = 0; ii < IPB; ii++)
#pragma unroll
      for (int q4 = 0; q4 < 4; q4++) {
        float4 v = wreg[ii * 4 + q4];
        int idx = q4 * 512 + tid;          // float4 index within W[i]
        int jd = idx >> 2, q = idx & 3;    // q = k/4
        u32* d = wfrag + (((size_t)ii * 16 + (jd >> 5)) * 64 +
                          (q & 1) * 32 + (jd & 31)) * 4 + (q >> 1) * 2;
        d[0] = pk2(v.x, v.y);
        d[1] = pk2(v.z, v.w);
      }
  }
  __syncthreads();

  cg::grid_group grid = cg::this_grid();
  const int icq = ic >> 3, ilo = ic & 7;

  for (int p = 0; p < 3; p++) {
    f32x16 sa[4];
#pragma unroll
    for (int m = 0; m < 4; m++)
#pragma unroll
      for (int q = 0; q < 16; q++) sa[m][q] = 0.f;

    float Sv[4][16];
    if (p != 0) {
#pragma unroll
      for (int m = 0; m < 4; m++) {
        int mt = wm * 4 + m;
#pragma unroll
        for (int r = 0; r < 16; r++) {
          int row = (r & 3) + 8 * (r >> 2) + 4 * hi;
          Sv[m][r] = ST[(size_t)(mt * 32 + row) * 64 + bg * 32 + col];
        }
      }
    }

    for (int ii = 0; ii < IPB; ii++) {
      s16x8 xv = *(const s16x8*)(xfrag + (((size_t)ii * 2 + bg) * 64 + l) * 4);
      s16x4 xlo = __builtin_shufflevector(xv, xv, 0, 1, 2, 3);
      s16x4 xhi = __builtin_shufflevector(xv, xv, 4, 5, 6, 7);

      f32x16 D[4];
#pragma unroll
      for (int m = 0; m < 4; m++) {
        int mt = wm * 4 + m;
        s16x8 wv = *(const s16x8*)(wfrag + (((size_t)ii * 16 + mt) * 64 + l) * 4);
        s16x4 wlo = __builtin_shufflevector(wv, wv, 0, 1, 2, 3);
        s16x4 whi = __builtin_shufflevector(wv, wv, 4, 5, 6, 7);
        f32x16 acc;
        if (p == 0) {
          acc = sa[m];
        } else {
#pragma unroll
          for (int q = 0; q < 16; q++) acc[q] = 0.f;
        }
        acc = __builtin_amdgcn_mfma_f32_32x32x8bf16_1k(wlo, xlo, acc, 0, 0, 0);
        acc = __builtin_amdgcn_mfma_f32_32x32x8bf16_1k(whi, xhi, acc, 0, 0, 0);
        if (p == 0) sa[m] = acc; else D[m] = acc;
      }

      if (p != 0) {
        // logits -> exp in-register; only partial Z crosses waves
        float ee[4], eo[4], zl = 0.f;
#pragma unroll
        for (int m = 0; m < 4; m++) {
          float pe = 0.f, po = 0.f;
#pragma unroll
          for (int r = 0; r < 8; r++) pe += D[m][r] * Sv[m][r];
#pragma unroll
          for (int r = 0; r < 8; r++) po += D[m][r + 8] * Sv[m][r + 8];
          pe += __shfl_xor(pe, 32);   // other d-half lives in lane^32
          po += __shfl_xor(po, 32);
          ee[m] = __expf(pe);
          eo[m] = __expf(po);
          zl += ee[m] + eo[m];
        }
        if (l < 32) zbuf[((ii & 1) * 8 + w) * 33 + col] = zl;
        __syncthreads();
        // softmax over j=32 for this bg: sum this bg's 4 wave-partials
        float Z = zbuf[((ii & 1) * 8 + bg * 4 + 0) * 33 + col] +
                  zbuf[((ii & 1) * 8 + bg * 4 + 1) * 33 + col] +
                  zbuf[((ii & 1) * 8 + bg * 4 + 2) * 33 + col] +
                  zbuf[((ii & 1) * 8 + bg * 4 + 3) * 33 + col];
        float rz = 1.0f / Z;
#pragma unroll
        for (int m = 0; m < 4; m++) {
          float ce = ee[m] * rz, co = eo[m] * rz;
#pragma unroll
          for (int r = 0; r < 8; r++) sa[m][r]     += ce * D[m][r];
#pragma unroll
          for (int r = 0; r < 8; r++) sa[m][r + 8] += co * D[m][r + 8];
        }
      }
    }

    // ---- publish per-block partial s: part[bg][jd][icq][b][ilo] fp16 ----
    const float sc = (p == 0) ? (1.0f / 32.0f) : 1.0f;
#pragma unroll
    for (int m = 0; m < 4; m++) {
      int mt = wm * 4 + m;
#pragma unroll
      for (int r = 0; r < 16; r++) {
        int row = (r & 3) + 8 * (r >> 2) + 4 * hi;
        int jd = mt * 32 + row;
        part[((((size_t)bg * JDIM + jd) * 32 + icq) * 32 + col) * 8 + ilo] =
            (_Float16)(sa[m][r] * sc);
      }
    }
    __threadfence();
    grid.sync();
    __threadfence();

    // ---- reduce + squash + ST/out update (blocks 0..63) ----
    if (blockIdx.x < 64) {
      int rbg = (int)blockIdx.x & 1, j = (int)blockIdx.x >> 1;
      int d = tid >> 5, b = tid & 31;
      int jd = j * 16 + d;
      const _Float16* pb = part + (((size_t)rbg * JDIM + jd) * 1024 + b) * 8;
      float a0 = 0.f, a1 = 0.f, a2 = 0.f, a3 = 0.f;
#pragma unroll
      for (int q = 0; q < 32; q += 4) {
        a0 += sum8(*(const h16x8*)(pb + (size_t)(q + 0) * 256));
        a1 += sum8(*(const h16x8*)(pb + (size_t)(q + 1) * 256));
        a2 += sum8(*(const h16x8*)(pb + (size_t)(q + 2) * 256));
        a3 += sum8(*(const h16x8*)(pb + (size_t)(q + 3) * 256));
      }
      float s = (a0 + a1) + (a2 + a3);
      sl[d * 33 + b] = s * s;
      __syncthreads();
      float s2 = 0.f;
#pragma unroll
      for (int dd = 0; dd < 16; dd++) s2 += sl[dd * 33 + b];
      float o = s * s2 / ((1.0f + s2) * sqrtf(s2 + EPS_SQ));
      if (p == 2) {
        out[((size_t)(rbg * 32 + b) * 32 + j) * 16 + d] = o;
      } else {
        size_t sti = (size_t)jd * 64 + rbg * 32 + b;
        ST[sti] = (p == 0 ? 0.f : ST[sti]) + o;
      }
    }
    if (p < 2) {
      __threadfence();
      grid.sync();
      __threadfence();
    }
  }
}

// ---------------------------------------------------------------------------
extern "C" void kernel_launch(void* const* d_in, const int* in_sizes, int n_in,
                              void* d_out, int out_size, void* d_ws, size_t ws_size,
                              hipStream_t stream) {
  (void)in_sizes; (void)n_in; (void)out_size;
  const float* x = (const float*)d_in[0];
  const float* W = (const float*)d_in[1];
  float* out = (float*)d_out;

  float*    ST   = (float*)d_ws;                                  // 128 KB
  _Float16* part = (_Float16*)((char*)d_ws + (256 << 10));        // 16.78 MB
  const size_t need = (256 << 10) + (size_t)2 * JDIM * 32 * 32 * 8 * 2 + 1024;
  fprintf(stderr, "[caps] ws_size=%zu need=%zu lds=%d\n", ws_size, need, LDS_BYTES);
  if (ws_size < need) return;

  hipFuncSetAttribute(reinterpret_cast<const void*>(k_all),
                      hipFuncAttributeMaxDynamicSharedMemorySize, LDS_BYTES);

  void* args[] = {(void*)&W, (void*)&x, (void*)&out, (void*)&ST, (void*)&part};
  hipLaunchCooperativeKernel(reinterpret_cast<const void*>(k_all),
                             dim3(NBLK), dim3(512), args, LDS_BYTES, stream);
}

// Round 5
// 956.096 us; speedup vs baseline: 1.0330x; 1.0330x over previous
//
#include <hip/hip_runtime.h>
#include <hip/hip_cooperative_groups.h>
#include <cstdio>

namespace cg = cooperative_groups;

// CapsuleLayer dynamic routing, MI355X (gfx950). Round 5.
// Round-4 post-mortem: __launch_bounds__(512,2) forced a 128-VGPR cap ->
// ~600 MB scratch spill (WRITE_SIZE 568 MB), 988 us. Structure was sound.
// Fixes: (1) __launch_bounds__(512) -> up to 256 VGPR, 1 block/CU;
//        (2) W staged in 8 chunks of 4 float4 (16 regs), no wreg[32] array;
//        (3) Sv packed bf16 (32 regs, validated round 2).
// Design: ONE cooperative kernel, 256 blocks (1/CU) x 512 thr (8 waves).
//  - Block stages its 8-capsule W slice ONCE into LDS as bf16 MFMA A-frags
//    (128 KB) + x B-frags (16 KB); reused across all 3 routing passes.
//  - Waves 0-3 = batch-group 0, waves 4-7 = bg 1; wave owns 4 mt-tiles.
//  - Per-pass cross-block reduction via part[bg][jd][icq][b][ilo] fp16 in ws
//    (L3-resident), grid.sync(), blocks 0..63 reduce+squash+ST, grid.sync().
//  - Softmax without max-subtract (logits bounded); only per-wave partial Z
//    crosses waves; one block barrier per i-iteration (parity dbuf).

#define IPB   8
#define NBLK  256
#define JDIM  512
#define EPS_SQ 1e-7f

typedef short    s16x4  __attribute__((ext_vector_type(4)));
typedef short    s16x8  __attribute__((ext_vector_type(8)));
typedef float    f32x16 __attribute__((ext_vector_type(16)));
typedef _Float16 h16x8  __attribute__((ext_vector_type(8)));
typedef unsigned u32;

// LDS layout in u32 units
#define WF_OFF 0                    // wfrag [8 i][16 mt][64 l][4]  = 131072 B
#define XF_OFF 32768                // xfrag [8 i][2 bg][64 l][4]   =  16384 B
#define ZB_OFF 36864                // zbuf  [2][8 w][33] float     =   2112 B
#define SL_OFF (ZB_OFF + 528)       // sl    [16][33] float         =   2112 B
#define LDS_U32 (SL_OFF + 528)
#define LDS_BYTES (LDS_U32 * 4)     // 151,680 B (< 160 KiB)

__device__ inline short bfc(float f) {
  u32 u = __builtin_bit_cast(u32, f);
  u32 r = (u + 0x7FFFu + ((u >> 16) & 1u)) >> 16;
  return (short)(unsigned short)r;
}
__device__ inline u32 pk2(float a, float b) {
  return (u32)(unsigned short)bfc(a) | ((u32)(unsigned short)bfc(b) << 16);
}
__device__ inline float bf2f(short s) {
  return __builtin_bit_cast(float, ((u32)(unsigned short)s) << 16);
}
__device__ inline float sum8(h16x8 v) {
  return (((float)v[0] + (float)v[1]) + ((float)v[2] + (float)v[3])) +
         (((float)v[4] + (float)v[5]) + ((float)v[6] + (float)v[7]));
}

__global__ __launch_bounds__(512) void k_all(const float* __restrict__ W,
                                             const float* __restrict__ x,
                                             float* __restrict__ out,
                                             float* __restrict__ ST,
                                             _Float16* __restrict__ part) {
  extern __shared__ u32 lds[];
  u32*   wfrag = lds + WF_OFF;
  u32*   xfrag = lds + XF_OFF;
  float* zbuf  = (float*)(lds + ZB_OFF);
  float* sl    = (float*)(lds + SL_OFF);

  const int ic  = blockIdx.x;
  const int tid = threadIdx.x;
  const int w   = tid >> 6;
  const int l   = tid & 63;
  const int col = l & 31;
  const int hi  = l >> 5;
  const int bg  = w >> 2;          // waves 0-3: batch 0-31, waves 4-7: 32-63
  const int wm  = w & 3;           // mt = wm*4 + m
  const int i0  = ic * IPB;

  // ---------------- stage x + W into LDS fragments (once) ----------------
  {
    // x: thread t -> row (b = t>>3, i = i0 + (t&7)), 16 floats contiguous
    const int xb = tid >> 3, xi = tid & 7;
    const float* xsrc = x + ((size_t)xb * 2048 + i0 + xi) * 16;
    float4 xv0 = *(const float4*)(xsrc);
    float4 xv1 = *(const float4*)(xsrc + 4);
    float4 xv2 = *(const float4*)(xsrc + 8);
    float4 xv3 = *(const float4*)(xsrc + 12);
    {
      int lbg = xb >> 5, lc = xb & 31;
      u32* d0 = xfrag + (((size_t)xi * 2 + lbg) * 64 + lc) * 4;       // hi=0
      d0[0] = pk2(xv0.x, xv0.y); d0[1] = pk2(xv0.z, xv0.w);
      d0[2] = pk2(xv2.x, xv2.y); d0[3] = pk2(xv2.z, xv2.w);
      u32* d1 = d0 + 32 * 4;                                          // hi=1
      d1[0] = pk2(xv1.x, xv1.y); d1[1] = pk2(xv1.z, xv1.w);
      d1[2] = pk2(xv3.x, xv3.y); d1[3] = pk2(xv3.z, xv3.w);
    }
    // W: 8 chunks of 4 float4 -> bounded register pressure, pipelined loads
    const float* wsrc = W + (size_t)i0 * 8192;
#pragma unroll
    for (int ii = 0; ii < IPB; ii++) {
      float4 v0 = *(const float4*)(wsrc + (size_t)ii * 8192 + (size_t)(0 * 512 + tid) * 4);
      float4 v1 = *(const float4*)(wsrc + (size_t)ii * 8192 + (size_t)(1 * 512 + tid) * 4);
      float4 v2 = *(const float4*)(wsrc + (size_t)ii * 8192 + (size_t)(2 * 512 + tid) * 4);
      float4 v3 = *(const float4*)(wsrc + (size_t)ii * 8192 + (size_t)(3 * 512 + tid) * 4);
#pragma unroll
      for (int q4 = 0; q4 < 4; q4++) {
        float4 v = (q4 == 0) ? v0 : (q4 == 1) ? v1 : (q4 == 2) ? v2 : v3;
        int idx = q4 * 512 + tid;          // float4 index within W[i]
        int jd = idx >> 2, q = idx & 3;    // q = k/4
        u32* d = wfrag + (((size_t)ii * 16 + (jd >> 5)) * 64 +
                          (q & 1) * 32 + (jd & 31)) * 4 + (q >> 1) * 2;
        d[0] = pk2(v.x, v.y);
        d[1] = pk2(v.z, v.w);
      }
    }
  }
  __syncthreads();

  cg::grid_group grid = cg::this_grid();
  const int icq = ic >> 3, ilo = ic & 7;

  for (int p = 0; p < 3; p++) {
    f32x16 sa[4];
#pragma unroll
    for (int m = 0; m < 4; m++)
#pragma unroll
      for (int q = 0; q < 16; q++) sa[m][q] = 0.f;

    // S (cumulative outputs), packed bf16: svA = acc rows r0..7, svB = r8..15
    s16x8 svA[4], svB[4];
    if (p != 0) {
#pragma unroll
      for (int m = 0; m < 4; m++) {
        int mt = wm * 4 + m;
#pragma unroll
        for (int r = 0; r < 16; r++) {
          int row = (r & 3) + 8 * (r >> 2) + 4 * hi;
          float v = ST[(size_t)(mt * 32 + row) * 64 + bg * 32 + col];
          short h = bfc(v);
          if (r < 8) svA[m][r] = h; else svB[m][r - 8] = h;
        }
      }
    }

    for (int ii = 0; ii < IPB; ii++) {
      s16x8 xv = *(const s16x8*)(xfrag + (((size_t)ii * 2 + bg) * 64 + l) * 4);
      s16x4 xlo = __builtin_shufflevector(xv, xv, 0, 1, 2, 3);
      s16x4 xhi = __builtin_shufflevector(xv, xv, 4, 5, 6, 7);

      f32x16 D[4];
#pragma unroll
      for (int m = 0; m < 4; m++) {
        int mt = wm * 4 + m;
        s16x8 wv = *(const s16x8*)(wfrag + (((size_t)ii * 16 + mt) * 64 + l) * 4);
        s16x4 wlo = __builtin_shufflevector(wv, wv, 0, 1, 2, 3);
        s16x4 whi = __builtin_shufflevector(wv, wv, 4, 5, 6, 7);
        f32x16 acc;
        if (p == 0) {
          acc = sa[m];
        } else {
#pragma unroll
          for (int q = 0; q < 16; q++) acc[q] = 0.f;
        }
        acc = __builtin_amdgcn_mfma_f32_32x32x8bf16_1k(wlo, xlo, acc, 0, 0, 0);
        acc = __builtin_amdgcn_mfma_f32_32x32x8bf16_1k(whi, xhi, acc, 0, 0, 0);
        if (p == 0) sa[m] = acc; else D[m] = acc;
      }

      if (p != 0) {
        // logits -> exp in-register; only partial Z crosses waves
        float ee[4], eo[4], zl = 0.f;
#pragma unroll
        for (int m = 0; m < 4; m++) {
          float pe = 0.f, po = 0.f;
#pragma unroll
          for (int r = 0; r < 8; r++) pe += D[m][r]     * bf2f(svA[m][r]);
#pragma unroll
          for (int r = 0; r < 8; r++) po += D[m][r + 8] * bf2f(svB[m][r]);
          pe += __shfl_xor(pe, 32);   // other d-half lives in lane^32
          po += __shfl_xor(po, 32);
          ee[m] = __expf(pe);
          eo[m] = __expf(po);
          zl += ee[m] + eo[m];
        }
        if (l < 32) zbuf[((ii & 1) * 8 + w) * 33 + col] = zl;
        __syncthreads();
        // softmax over j=32 for this bg: sum this bg's 4 wave-partials
        float Z = zbuf[((ii & 1) * 8 + bg * 4 + 0) * 33 + col] +
                  zbuf[((ii & 1) * 8 + bg * 4 + 1) * 33 + col] +
                  zbuf[((ii & 1) * 8 + bg * 4 + 2) * 33 + col] +
                  zbuf[((ii & 1) * 8 + bg * 4 + 3) * 33 + col];
        float rz = 1.0f / Z;
#pragma unroll
        for (int m = 0; m < 4; m++) {
          float ce = ee[m] * rz, co = eo[m] * rz;
#pragma unroll
          for (int r = 0; r < 8; r++) sa[m][r]     += ce * D[m][r];
#pragma unroll
          for (int r = 0; r < 8; r++) sa[m][r + 8] += co * D[m][r + 8];
        }
      }
    }

    // ---- publish per-block partial s: part[bg][jd][icq][b][ilo] fp16 ----
    const float sc = (p == 0) ? (1.0f / 32.0f) : 1.0f;
#pragma unroll
    for (int m = 0; m < 4; m++) {
      int mt = wm * 4 + m;
#pragma unroll
      for (int r = 0; r < 16; r++) {
        int row = (r & 3) + 8 * (r >> 2) + 4 * hi;
        int jd = mt * 32 + row;
        part[((((size_t)bg * JDIM + jd) * 32 + icq) * 32 + col) * 8 + ilo] =
            (_Float16)(sa[m][r] * sc);
      }
    }
    __threadfence();
    grid.sync();
    __threadfence();

    // ---- reduce + squash + ST/out update (blocks 0..63) ----
    if (blockIdx.x < 64) {
      int rbg = (int)blockIdx.x & 1, j = (int)blockIdx.x >> 1;
      int d = tid >> 5, b = tid & 31;
      int jd = j * 16 + d;
      const _Float16* pb = part + (((size_t)rbg * JDIM + jd) * 1024 + b) * 8;
      float a0 = 0.f, a1 = 0.f, a2 = 0.f, a3 = 0.f;
#pragma unroll
      for (int q = 0; q < 32; q += 4) {
        a0 += sum8(*(const h16x8*)(pb + (size_t)(q + 0) * 256));
        a1 += sum8(*(const h16x8*)(pb + (size_t)(q + 1) * 256));
        a2 += sum8(*(const h16x8*)(pb + (size_t)(q + 2) * 256));
        a3 += sum8(*(const h16x8*)(pb + (size_t)(q + 3) * 256));
      }
      float s = (a0 + a1) + (a2 + a3);
      sl[d * 33 + b] = s * s;
      __syncthreads();
      float s2 = 0.f;
#pragma unroll
      for (int dd = 0; dd < 16; dd++) s2 += sl[dd * 33 + b];
      float o = s * s2 / ((1.0f + s2) * sqrtf(s2 + EPS_SQ));
      if (p == 2) {
        out[((size_t)(rbg * 32 + b) * 32 + j) * 16 + d] = o;
      } else {
        size_t sti = (size_t)jd * 64 + rbg * 32 + b;
        ST[sti] = (p == 0 ? 0.f : ST[sti]) + o;
      }
    }
    if (p < 2) {
      __threadfence();
      grid.sync();
      __threadfence();
    }
  }
}

// ---------------------------------------------------------------------------
extern "C" void kernel_launch(void* const* d_in, const int* in_sizes, int n_in,
                              void* d_out, int out_size, void* d_ws, size_t ws_size,
                              hipStream_t stream) {
  (void)in_sizes; (void)n_in; (void)out_size;
  const float* x = (const float*)d_in[0];
  const float* W = (const float*)d_in[1];
  float* out = (float*)d_out;

  float*    ST   = (float*)d_ws;                                  // 128 KB
  _Float16* part = (_Float16*)((char*)d_ws + (256 << 10));        // 16.78 MB
  const size_t need = (256 << 10) + (size_t)2 * JDIM * 32 * 32 * 8 * 2 + 1024;
  fprintf(stderr, "[caps] ws_size=%zu need=%zu lds=%d\n", ws_size, need, LDS_BYTES);
  if (ws_size < need) return;

  hipFuncSetAttribute(reinterpret_cast<const void*>(k_all),
                      hipFuncAttributeMaxDynamicSharedMemorySize, LDS_BYTES);

  void* args[] = {(void*)&W, (void*)&x, (void*)&out, (void*)&ST, (void*)&part};
  hipLaunchCooperativeKernel(reinterpret_cast<const void*>(k_all),
                             dim3(NBLK), dim3(512), args, LDS_BYTES, stream);
}

// Round 6
// 840.456 us; speedup vs baseline: 1.1751x; 1.1376x over previous
//
#include <hip/hip_runtime.h>
#include <hip/hip_cooperative_groups.h>
#include <cstdio>

namespace cg = cooperative_groups;

// CapsuleLayer dynamic routing, MI355X (gfx950). Round 6.
// Round-5 post-mortem: 956us was NOT spill. part layout [..icq][b][ilo] put
// ilo=ic&7 innermost -> each 16B segment written 2B-at-a-time by 8 DIFFERENT
// workgroups (different XCDs) -> partial-line RMW false sharing, ~540 MB
// writes + 195 MB fetches; dur == hbm_bytes/BW. Fix: revert to round-3's
// coalesced layout part[bg][jd][ic][col] (col innermost: one wave writes each
// 64B line exactly once). Everything else unchanged from round 5.
// Design: ONE cooperative kernel, 256 blocks (1/CU) x 512 thr (8 waves).
//  - Block stages its 8-capsule W slice ONCE into LDS as bf16 MFMA A-frags
//    (128 KB) + x B-frags (16 KB); reused across all 3 routing passes.
//  - Waves 0-3 = batch-group 0, waves 4-7 = bg 1; wave owns 4 mt-tiles.
//  - Per-pass cross-block reduction via part (L3-resident) + grid.sync();
//    blocks 0..63 reduce+squash+ST/out update; grid.sync().
//  - Softmax without max-subtract (logits bounded); only per-wave partial Z
//    crosses waves; one block barrier per i-iteration (parity dbuf).

#define IPB   8
#define NBLK  256
#define JDIM  512
#define EPS_SQ 1e-7f

typedef short    s16x4  __attribute__((ext_vector_type(4)));
typedef short    s16x8  __attribute__((ext_vector_type(8)));
typedef float    f32x16 __attribute__((ext_vector_type(16)));
typedef unsigned u32;

// LDS layout in u32 units
#define WF_OFF 0                    // wfrag [8 i][16 mt][64 l][4]  = 131072 B
#define XF_OFF 32768                // xfrag [8 i][2 bg][64 l][4]   =  16384 B
#define ZB_OFF 36864                // zbuf  [2][8 w][33] float     =   2112 B
#define SL_OFF (ZB_OFF + 528)       // sl    [16][33] float         =   2112 B
#define LDS_U32 (SL_OFF + 528)
#define LDS_BYTES (LDS_U32 * 4)     // 151,680 B (< 160 KiB)

__device__ inline short bfc(float f) {
  u32 u = __builtin_bit_cast(u32, f);
  u32 r = (u + 0x7FFFu + ((u >> 16) & 1u)) >> 16;
  return (short)(unsigned short)r;
}
__device__ inline u32 pk2(float a, float b) {
  return (u32)(unsigned short)bfc(a) | ((u32)(unsigned short)bfc(b) << 16);
}
__device__ inline float bf2f(short s) {
  return __builtin_bit_cast(float, ((u32)(unsigned short)s) << 16);
}

__global__ __launch_bounds__(512) void k_all(const float* __restrict__ W,
                                             const float* __restrict__ x,
                                             float* __restrict__ out,
                                             float* __restrict__ ST,
                                             _Float16* __restrict__ part) {
  extern __shared__ u32 lds[];
  u32*   wfrag = lds + WF_OFF;
  u32*   xfrag = lds + XF_OFF;
  float* zbuf  = (float*)(lds + ZB_OFF);
  float* sl    = (float*)(lds + SL_OFF);

  const int ic  = blockIdx.x;
  const int tid = threadIdx.x;
  const int w   = tid >> 6;
  const int l   = tid & 63;
  const int col = l & 31;
  const int hi  = l >> 5;
  const int bg  = w >> 2;          // waves 0-3: batch 0-31, waves 4-7: 32-63
  const int wm  = w & 3;           // mt = wm*4 + m
  const int i0  = ic * IPB;

  // ---------------- stage x + W into LDS fragments (once) ----------------
  {
    // x: thread t -> row (b = t>>3, i = i0 + (t&7)), 16 floats contiguous
    const int xb = tid >> 3, xi = tid & 7;
    const float* xsrc = x + ((size_t)xb * 2048 + i0 + xi) * 16;
    float4 xv0 = *(const float4*)(xsrc);
    float4 xv1 = *(const float4*)(xsrc + 4);
    float4 xv2 = *(const float4*)(xsrc + 8);
    float4 xv3 = *(const float4*)(xsrc + 12);
    {
      int lbg = xb >> 5, lc = xb & 31;
      u32* d0 = xfrag + (((size_t)xi * 2 + lbg) * 64 + lc) * 4;       // hi=0
      d0[0] = pk2(xv0.x, xv0.y); d0[1] = pk2(xv0.z, xv0.w);
      d0[2] = pk2(xv2.x, xv2.y); d0[3] = pk2(xv2.z, xv2.w);
      u32* d1 = d0 + 32 * 4;                                          // hi=1
      d1[0] = pk2(xv1.x, xv1.y); d1[1] = pk2(xv1.z, xv1.w);
      d1[2] = pk2(xv3.x, xv3.y); d1[3] = pk2(xv3.z, xv3.w);
    }
    // W: 8 chunks of 4 float4 -> bounded register pressure, pipelined loads
    const float* wsrc = W + (size_t)i0 * 8192;
#pragma unroll
    for (int ii = 0; ii < IPB; ii++) {
      float4 v0 = *(const float4*)(wsrc + (size_t)ii * 8192 + (size_t)(0 * 512 + tid) * 4);
      float4 v1 = *(const float4*)(wsrc + (size_t)ii * 8192 + (size_t)(1 * 512 + tid) * 4);
      float4 v2 = *(const float4*)(wsrc + (size_t)ii * 8192 + (size_t)(2 * 512 + tid) * 4);
      float4 v3 = *(const float4*)(wsrc + (size_t)ii * 8192 + (size_t)(3 * 512 + tid) * 4);
#pragma unroll
      for (int q4 = 0; q4 < 4; q4++) {
        float4 v = (q4 == 0) ? v0 : (q4 == 1) ? v1 : (q4 == 2) ? v2 : v3;
        int idx = q4 * 512 + tid;          // float4 index within W[i]
        int jd = idx >> 2, q = idx & 3;    // q = k/4
        u32* d = wfrag + (((size_t)ii * 16 + (jd >> 5)) * 64 +
                          (q & 1) * 32 + (jd & 31)) * 4 + (q >> 1) * 2;
        d[0] = pk2(v.x, v.y);
        d[1] = pk2(v.z, v.w);
      }
    }
  }
  __syncthreads();

  cg::grid_group grid = cg::this_grid();

  for (int p = 0; p < 3; p++) {
    f32x16 sa[4];
#pragma unroll
    for (int m = 0; m < 4; m++)
#pragma unroll
      for (int q = 0; q < 16; q++) sa[m][q] = 0.f;

    // S (cumulative outputs), packed bf16: svA = acc rows r0..7, svB = r8..15
    s16x8 svA[4], svB[4];
    if (p != 0) {
#pragma unroll
      for (int m = 0; m < 4; m++) {
        int mt = wm * 4 + m;
#pragma unroll
        for (int r = 0; r < 16; r++) {
          int row = (r & 3) + 8 * (r >> 2) + 4 * hi;
          float v = ST[(size_t)(mt * 32 + row) * 64 + bg * 32 + col];
          short h = bfc(v);
          if (r < 8) svA[m][r] = h; else svB[m][r - 8] = h;
        }
      }
    }

    for (int ii = 0; ii < IPB; ii++) {
      s16x8 xv = *(const s16x8*)(xfrag + (((size_t)ii * 2 + bg) * 64 + l) * 4);
      s16x4 xlo = __builtin_shufflevector(xv, xv, 0, 1, 2, 3);
      s16x4 xhi = __builtin_shufflevector(xv, xv, 4, 5, 6, 7);

      f32x16 D[4];
#pragma unroll
      for (int m = 0; m < 4; m++) {
        int mt = wm * 4 + m;
        s16x8 wv = *(const s16x8*)(wfrag + (((size_t)ii * 16 + mt) * 64 + l) * 4);
        s16x4 wlo = __builtin_shufflevector(wv, wv, 0, 1, 2, 3);
        s16x4 whi = __builtin_shufflevector(wv, wv, 4, 5, 6, 7);
        f32x16 acc;
        if (p == 0) {
          acc = sa[m];
        } else {
#pragma unroll
          for (int q = 0; q < 16; q++) acc[q] = 0.f;
        }
        acc = __builtin_amdgcn_mfma_f32_32x32x8bf16_1k(wlo, xlo, acc, 0, 0, 0);
        acc = __builtin_amdgcn_mfma_f32_32x32x8bf16_1k(whi, xhi, acc, 0, 0, 0);
        if (p == 0) sa[m] = acc; else D[m] = acc;
      }

      if (p != 0) {
        // logits -> exp in-register; only partial Z crosses waves
        float ee[4], eo[4], zl = 0.f;
#pragma unroll
        for (int m = 0; m < 4; m++) {
          float pe = 0.f, po = 0.f;
#pragma unroll
          for (int r = 0; r < 8; r++) pe += D[m][r]     * bf2f(svA[m][r]);
#pragma unroll
          for (int r = 0; r < 8; r++) po += D[m][r + 8] * bf2f(svB[m][r]);
          pe += __shfl_xor(pe, 32);   // other d-half lives in lane^32
          po += __shfl_xor(po, 32);
          ee[m] = __expf(pe);
          eo[m] = __expf(po);
          zl += ee[m] + eo[m];
        }
        if (l < 32) zbuf[((ii & 1) * 8 + w) * 33 + col] = zl;
        __syncthreads();
        // softmax over j=32 for this bg: sum this bg's 4 wave-partials
        float Z = zbuf[((ii & 1) * 8 + bg * 4 + 0) * 33 + col] +
                  zbuf[((ii & 1) * 8 + bg * 4 + 1) * 33 + col] +
                  zbuf[((ii & 1) * 8 + bg * 4 + 2) * 33 + col] +
                  zbuf[((ii & 1) * 8 + bg * 4 + 3) * 33 + col];
        float rz = 1.0f / Z;
#pragma unroll
        for (int m = 0; m < 4; m++) {
          float ce = ee[m] * rz, co = eo[m] * rz;
#pragma unroll
          for (int r = 0; r < 8; r++) sa[m][r]     += ce * D[m][r];
#pragma unroll
          for (int r = 0; r < 8; r++) sa[m][r + 8] += co * D[m][r + 8];
        }
      }
    }

    // ---- publish partial s: part[bg][jd][ic][col] fp16 (col innermost:
    //      each (m,r) half-wave writes one 64B line exactly once) ----
    const float sc = (p == 0) ? (1.0f / 32.0f) : 1.0f;
#pragma unroll
    for (int m = 0; m < 4; m++) {
      int mt = wm * 4 + m;
#pragma unroll
      for (int r = 0; r < 16; r++) {
        int row = (r & 3) + 8 * (r >> 2) + 4 * hi;
        int jd = mt * 32 + row;
        part[(((size_t)bg * JDIM + jd) * NBLK + ic) * 32 + col] =
            (_Float16)(sa[m][r] * sc);
      }
    }
    __threadfence();
    grid.sync();
    __threadfence();

    // ---- reduce + squash + ST/out update (blocks 0..63) ----
    if (blockIdx.x < 64) {
      int rbg = (int)blockIdx.x & 1, j = (int)blockIdx.x >> 1;
      int d = tid >> 5, b = tid & 31;
      int jd = j * 16 + d;
      const _Float16* pb = part + ((size_t)(rbg * JDIM + jd) * NBLK) * 32 + b;
      float a0 = 0.f, a1 = 0.f, a2 = 0.f, a3 = 0.f;
#pragma unroll 8
      for (int q = 0; q < NBLK; q += 4) {
        a0 += (float)pb[(size_t)(q + 0) * 32];
        a1 += (float)pb[(size_t)(q + 1) * 32];
        a2 += (float)pb[(size_t)(q + 2) * 32];
        a3 += (float)pb[(size_t)(q + 3) * 32];
      }
      float s = (a0 + a1) + (a2 + a3);
      sl[d * 33 + b] = s * s;
      __syncthreads();
      float s2 = 0.f;
#pragma unroll
      for (int dd = 0; dd < 16; dd++) s2 += sl[dd * 33 + b];
      float o = s * s2 / ((1.0f + s2) * sqrtf(s2 + EPS_SQ));
      if (p == 2) {
        out[((size_t)(rbg * 32 + b) * 32 + j) * 16 + d] = o;
      } else {
        size_t sti = (size_t)jd * 64 + rbg * 32 + b;
        ST[sti] = (p == 0 ? 0.f : ST[sti]) + o;
      }
    }
    if (p < 2) {
      __threadfence();
      grid.sync();
      __threadfence();
    }
  }
}

// ---------------------------------------------------------------------------
extern "C" void kernel_launch(void* const* d_in, const int* in_sizes, int n_in,
                              void* d_out, int out_size, void* d_ws, size_t ws_size,
                              hipStream_t stream) {
  (void)in_sizes; (void)n_in; (void)out_size;
  const float* x = (const float*)d_in[0];
  const float* W = (const float*)d_in[1];
  float* out = (float*)d_out;

  float*    ST   = (float*)d_ws;                                  // 128 KB
  _Float16* part = (_Float16*)((char*)d_ws + (256 << 10));        // 16.78 MB
  const size_t need = (256 << 10) + (size_t)2 * JDIM * NBLK * 32 * 2 + 1024;
  fprintf(stderr, "[caps] ws_size=%zu need=%zu lds=%d\n", ws_size, need, LDS_BYTES);
  if (ws_size < need) return;

  hipFuncSetAttribute(reinterpret_cast<const void*>(k_all),
                      hipFuncAttributeMaxDynamicSharedMemorySize, LDS_BYTES);

  void* args[] = {(void*)&W, (void*)&x, (void*)&out, (void*)&ST, (void*)&part};
  hipLaunchCooperativeKernel(reinterpret_cast<const void*>(k_all),
                             dim3(NBLK), dim3(512), args, LDS_BYTES, stream);
}

// Round 7
// 313.960 us; speedup vs baseline: 3.1457x; 2.6770x over previous
//
#include <hip/hip_runtime.h>
#include <cstdio>

// CapsuleLayer dynamic routing, MI355X (gfx950). Round 7.
// Round-6 post-mortem: cooperative kernel's ~750us constant is grid.sync
// and/or partial spill of the heavy 8-wave p!=0 body at 128 VGPR (rounds
// 4/5/6 all VGPR=128; ~90MB unexplained writes). Drop cooperative entirely.
// Structure (6 ordinary launches):
//  1. k_pass0: 256 blk x 512 thr. Stage W+x -> LDS bf16 MFMA frags (round-6
//     staging), run pass 0 (uniform c) from LDS, AND write Wp/xp to ws for
//     later passes (no separate prep kernel, W read from HBM exactly once).
//  2. k_rs<0>: 64 blk. Reduce part over ic + squash -> ST.   (fused red+squash)
//  3. k_passN: 512 blk x 512 thr, wave owns 2 mt (light regs, no spill),
//     streams Wp/xp global->reg->MFMA, 1-barrier softmax, part out.
//  4. k_rs<1>  5. k_passN  6. k_rs<2> -> out.

#define NC     32
#define JDIM   512
#define NICB   256          // i-chunk count (part's ic dimension)
#define IPB    8
#define EPS_SQ 1e-7f

typedef short    s16x4  __attribute__((ext_vector_type(4)));
typedef short    s16x8  __attribute__((ext_vector_type(8)));
typedef float    f32x16 __attribute__((ext_vector_type(16)));
typedef unsigned u32;

__device__ inline short bfc(float f) {
  u32 u = __builtin_bit_cast(u32, f);
  u32 r = (u + 0x7FFFu + ((u >> 16) & 1u)) >> 16;
  return (short)(unsigned short)r;
}
__device__ inline u32 pk2(float a, float b) {
  return (u32)(unsigned short)bfc(a) | ((u32)(unsigned short)bfc(b) << 16);
}
__device__ inline float bf2f(short s) {
  return __builtin_bit_cast(float, ((u32)(unsigned short)s) << 16);
}

// ---------------------------------------------------------------------------
// Pass 0 + fragment export. 256 blocks (ic) x 512 thr (8 waves).
// LDS: wfrag [8 i][16 mt][64 l][4 u32] = 128K ; xfrag [8 i][2 bg][64 l][4] = 16K.
// Waves 0-3: bg 0, waves 4-7: bg 1; wave owns mt = wm*4 + m (m<4).
// ---------------------------------------------------------------------------
__global__ __launch_bounds__(512) void k_pass0(const float* __restrict__ W,
                                               const float* __restrict__ x,
                                               unsigned short* __restrict__ Wp,
                                               unsigned short* __restrict__ xp,
                                               _Float16* __restrict__ part) {
  extern __shared__ u32 lds[];
  u32* wfrag = lds;             // 32768 u32
  u32* xfrag = lds + 32768;     // 4096 u32
  const int ic  = blockIdx.x;
  const int tid = threadIdx.x;
  const int w   = tid >> 6;
  const int l   = tid & 63;
  const int col = l & 31;
  const int hi  = l >> 5;
  const int bg  = w >> 2;
  const int wm  = w & 3;
  const int i0  = ic * IPB;

  // ---- stage x into LDS fragments ----
  {
    const int xb = tid >> 3, xi = tid & 7;
    const float* xsrc = x + ((size_t)xb * 2048 + i0 + xi) * 16;
    float4 xv0 = *(const float4*)(xsrc);
    float4 xv1 = *(const float4*)(xsrc + 4);
    float4 xv2 = *(const float4*)(xsrc + 8);
    float4 xv3 = *(const float4*)(xsrc + 12);
    int lbg = xb >> 5, lc = xb & 31;
    u32* d0 = xfrag + (((size_t)xi * 2 + lbg) * 64 + lc) * 4;       // hi=0
    d0[0] = pk2(xv0.x, xv0.y); d0[1] = pk2(xv0.z, xv0.w);
    d0[2] = pk2(xv2.x, xv2.y); d0[3] = pk2(xv2.z, xv2.w);
    u32* d1 = d0 + 32 * 4;                                          // hi=1
    d1[0] = pk2(xv1.x, xv1.y); d1[1] = pk2(xv1.z, xv1.w);
    d1[2] = pk2(xv3.x, xv3.y); d1[3] = pk2(xv3.z, xv3.w);
  }
  // ---- stage W into LDS fragments (coalesced reads, 4-float4 chunks) ----
  {
    const float* wsrc = W + (size_t)i0 * 8192;
#pragma unroll
    for (int ii = 0; ii < IPB; ii++) {
      float4 v0 = *(const float4*)(wsrc + (size_t)ii * 8192 + (size_t)(0 * 512 + tid) * 4);
      float4 v1 = *(const float4*)(wsrc + (size_t)ii * 8192 + (size_t)(1 * 512 + tid) * 4);
      float4 v2 = *(const float4*)(wsrc + (size_t)ii * 8192 + (size_t)(2 * 512 + tid) * 4);
      float4 v3 = *(const float4*)(wsrc + (size_t)ii * 8192 + (size_t)(3 * 512 + tid) * 4);
#pragma unroll
      for (int q4 = 0; q4 < 4; q4++) {
        float4 v = (q4 == 0) ? v0 : (q4 == 1) ? v1 : (q4 == 2) ? v2 : v3;
        int idx = q4 * 512 + tid;          // float4 index within W[i]
        int jd = idx >> 2, q = idx & 3;    // q = k/4
        u32* d = wfrag + (((size_t)ii * 16 + (jd >> 5)) * 64 +
                          (q & 1) * 32 + (jd & 31)) * 4 + (q >> 1) * 2;
        d[0] = pk2(v.x, v.y);
        d[1] = pk2(v.z, v.w);
      }
    }
  }
  __syncthreads();

  // ---- export fragments to global (coalesced LDS read + global store) ----
  {
    const size_t gfb = (size_t)ic * 8192;          // global frag base (i0*1024)
#pragma unroll
    for (int q = 0; q < 16; q++) {
      int fid = q * 512 + tid;                     // 0..8191
      uint4 v = *(const uint4*)(wfrag + (size_t)fid * 4);
      *(uint4*)(Wp + (gfb + fid) * 8) = v;
    }
    u32* xp32 = (u32*)xp;
#pragma unroll
    for (int q = 0; q < 2; q++) {
      int idx4 = q * 512 + tid;                    // uint4 index 0..1023
      uint4 v = *(const uint4*)(xfrag + (size_t)idx4 * 4);
      *(uint4*)(xp32 + (size_t)ic * 4096 + (size_t)idx4 * 4) = v;
    }
  }

  // ---- pass-0 compute (uniform c = 1/32): pure MFMA accumulate ----
  f32x16 sa[4];
#pragma unroll
  for (int m = 0; m < 4; m++)
#pragma unroll
    for (int q = 0; q < 16; q++) sa[m][q] = 0.f;

  for (int ii = 0; ii < IPB; ii++) {
    s16x8 xv = *(const s16x8*)(xfrag + (((size_t)ii * 2 + bg) * 64 + l) * 4);
    s16x4 xlo = __builtin_shufflevector(xv, xv, 0, 1, 2, 3);
    s16x4 xhi = __builtin_shufflevector(xv, xv, 4, 5, 6, 7);
#pragma unroll
    for (int m = 0; m < 4; m++) {
      int mt = wm * 4 + m;
      s16x8 wv = *(const s16x8*)(wfrag + (((size_t)ii * 16 + mt) * 64 + l) * 4);
      s16x4 wlo = __builtin_shufflevector(wv, wv, 0, 1, 2, 3);
      s16x4 whi = __builtin_shufflevector(wv, wv, 4, 5, 6, 7);
      sa[m] = __builtin_amdgcn_mfma_f32_32x32x8bf16_1k(wlo, xlo, sa[m], 0, 0, 0);
      sa[m] = __builtin_amdgcn_mfma_f32_32x32x8bf16_1k(whi, xhi, sa[m], 0, 0, 0);
    }
  }

#pragma unroll
  for (int m = 0; m < 4; m++) {
    int mt = wm * 4 + m;
#pragma unroll
    for (int r = 0; r < 16; r++) {
      int row = (r & 3) + 8 * (r >> 2) + 4 * hi;
      int jd = mt * 32 + row;
      part[(((size_t)bg * JDIM + jd) * NICB + ic) * 32 + col] =
          (_Float16)(sa[m][r] * (1.0f / 32.0f));
    }
  }
}

// ---------------------------------------------------------------------------
// Routing pass (p>=1). 512 blocks (bg = bid&1, ic = bid>>1) x 512 thr
// (8 waves, all same bg). Wave w owns mt = 2w, 2w+1. Streams Wp/xp from
// global (L3-hot) to registers; 1 barrier per i-iteration.
// ---------------------------------------------------------------------------
__global__ __launch_bounds__(512) void k_passN(const unsigned short* __restrict__ Wp,
                                               const unsigned short* __restrict__ xp,
                                               const float* __restrict__ ST,
                                               _Float16* __restrict__ part) {
  __shared__ float zbuf[2][8][33];
  const int bid = blockIdx.x;
  const int bg  = bid & 1;
  const int ic  = bid >> 1;
  const int tid = threadIdx.x;
  const int w   = tid >> 6;
  const int l   = tid & 63;
  const int col = l & 31;
  const int hi  = l >> 5;

  f32x16 sa[2];
#pragma unroll
  for (int m = 0; m < 2; m++)
#pragma unroll
    for (int q = 0; q < 16; q++) sa[m][q] = 0.f;

  // S packed bf16 (svA: acc rows 0..7 -> j even; svB: rows 8..15 -> j odd)
  s16x8 svA[2], svB[2];
#pragma unroll
  for (int m = 0; m < 2; m++) {
    int mt = w * 2 + m;
#pragma unroll
    for (int r = 0; r < 16; r++) {
      int row = (r & 3) + 8 * (r >> 2) + 4 * hi;
      short h = bfc(ST[(size_t)(mt * 32 + row) * 64 + bg * 32 + col]);
      if (r < 8) svA[m][r] = h; else svB[m][r - 8] = h;
    }
  }

  for (int ii = 0; ii < IPB; ii++) {
    int i = ic * IPB + ii;
    s16x8 xv = *(const s16x8*)(xp + ((size_t)i * 2 + bg) * 512 + (size_t)l * 8);
    s16x4 xlo = __builtin_shufflevector(xv, xv, 0, 1, 2, 3);
    s16x4 xhi = __builtin_shufflevector(xv, xv, 4, 5, 6, 7);

    f32x16 D[2];
#pragma unroll
    for (int m = 0; m < 2; m++) {
      int mt = w * 2 + m;
      s16x8 wv = *(const s16x8*)(Wp + (((size_t)i * 16 + mt) * 64 + l) * 8);
      s16x4 wlo = __builtin_shufflevector(wv, wv, 0, 1, 2, 3);
      s16x4 whi = __builtin_shufflevector(wv, wv, 4, 5, 6, 7);
      f32x16 acc;
#pragma unroll
      for (int q = 0; q < 16; q++) acc[q] = 0.f;
      acc = __builtin_amdgcn_mfma_f32_32x32x8bf16_1k(wlo, xlo, acc, 0, 0, 0);
      D[m] = __builtin_amdgcn_mfma_f32_32x32x8bf16_1k(whi, xhi, acc, 0, 0, 0);
    }

    // logits -> exp in-register; only partial Z crosses waves
    float ee[2], eo[2], zl = 0.f;
#pragma unroll
    for (int m = 0; m < 2; m++) {
      float pe = 0.f, po = 0.f;
#pragma unroll
      for (int r = 0; r < 8; r++) pe += D[m][r]     * bf2f(svA[m][r]);
#pragma unroll
      for (int r = 0; r < 8; r++) po += D[m][r + 8] * bf2f(svB[m][r]);
      pe += __shfl_xor(pe, 32);     // other d-half lives in lane^32
      po += __shfl_xor(po, 32);
      ee[m] = __expf(pe);
      eo[m] = __expf(po);
      zl += ee[m] + eo[m];
    }
    if (l < 32) zbuf[ii & 1][w][col] = zl;
    __syncthreads();
    float Z = 0.f;
#pragma unroll
    for (int ww = 0; ww < 8; ww++) Z += zbuf[ii & 1][ww][col];
    float rz = 1.0f / Z;
#pragma unroll
    for (int m = 0; m < 2; m++) {
      float ce = ee[m] * rz, co = eo[m] * rz;
#pragma unroll
      for (int r = 0; r < 8; r++) sa[m][r]     += ce * D[m][r];
#pragma unroll
      for (int r = 0; r < 8; r++) sa[m][r + 8] += co * D[m][r + 8];
    }
  }

#pragma unroll
  for (int m = 0; m < 2; m++) {
    int mt = w * 2 + m;
#pragma unroll
    for (int r = 0; r < 16; r++) {
      int row = (r & 3) + 8 * (r >> 2) + 4 * hi;
      int jd = mt * 32 + row;
      part[(((size_t)bg * JDIM + jd) * NICB + ic) * 32 + col] = (_Float16)sa[m][r];
    }
  }
}

// ---------------------------------------------------------------------------
// Fused reduce (over 256 ic) + squash + ST/out update. 64 blocks x 512 thr.
// P=0: ST = o ; P=1: ST += o ; P=2: out = o.
// ---------------------------------------------------------------------------
template <int P>
__global__ __launch_bounds__(512) void k_rs(const _Float16* __restrict__ part,
                                            float* __restrict__ ST,
                                            float* __restrict__ out) {
  __shared__ float sl[16][33];
  int bid = blockIdx.x;
  int rbg = bid & 1, j = bid >> 1;
  int t = threadIdx.x;
  int b = t & 31, d = t >> 5;
  int jd = j * 16 + d;
  const _Float16* pb = part + ((size_t)(rbg * JDIM + jd) * NICB) * 32 + b;
  float a[8];
#pragma unroll
  for (int k = 0; k < 8; k++) a[k] = 0.f;
  for (int q = 0; q < NICB; q += 8) {
#pragma unroll
    for (int k = 0; k < 8; k++) a[k] += (float)pb[(size_t)(q + k) * 32];
  }
  float s = ((a[0] + a[1]) + (a[2] + a[3])) + ((a[4] + a[5]) + (a[6] + a[7]));
  sl[d][b] = s * s;
  __syncthreads();
  float s2 = 0.f;
#pragma unroll
  for (int dd = 0; dd < 16; dd++) s2 += sl[dd][b];
  float o = s * s2 / ((1.0f + s2) * sqrtf(s2 + EPS_SQ));
  if (P == 2) {
    out[((size_t)(rbg * 32 + b) * NC + j) * 16 + d] = o;
  } else if (P == 0) {
    ST[(size_t)jd * 64 + rbg * 32 + b] = o;
  } else {
    ST[(size_t)jd * 64 + rbg * 32 + b] += o;
  }
}

// ---------------------------------------------------------------------------
extern "C" void kernel_launch(void* const* d_in, const int* in_sizes, int n_in,
                              void* d_out, int out_size, void* d_ws, size_t ws_size,
                              hipStream_t stream) {
  (void)in_sizes; (void)n_in; (void)out_size;
  const float* x = (const float*)d_in[0];
  const float* W = (const float*)d_in[1];
  float* out = (float*)d_out;

  const size_t off_st = 0;                                    // 128 KB (pad 256K)
  const size_t off_pt = (size_t)256 << 10;                    // 16.78 MB
  const size_t off_xp = off_pt + (size_t)2 * JDIM * NICB * 32 * 2;   // 4 MB
  const size_t off_wp = off_xp + (size_t)2048 * 2 * 512 * 2;          // 33.55 MB
  const size_t need   = off_wp + (size_t)2048 * 1024 * 16 + 1024;
  if (ws_size < need) { fprintf(stderr, "[caps] ws too small %zu < %zu\n", ws_size, need); return; }

  float*          ST   = (float*)((char*)d_ws + off_st);
  _Float16*       part = (_Float16*)((char*)d_ws + off_pt);
  unsigned short* xp   = (unsigned short*)((char*)d_ws + off_xp);
  unsigned short* Wp   = (unsigned short*)((char*)d_ws + off_wp);

  const int lds0 = 36864 * 4;   // 147456 B
  hipFuncSetAttribute(reinterpret_cast<const void*>(k_pass0),
                      hipFuncAttributeMaxDynamicSharedMemorySize, lds0);

  k_pass0<<<dim3(256), dim3(512), lds0, stream>>>(W, x, Wp, xp, part);
  k_rs<0><<<dim3(64), dim3(512), 0, stream>>>(part, ST, out);
  k_passN<<<dim3(512), dim3(512), 0, stream>>>(Wp, xp, ST, part);
  k_rs<1><<<dim3(64), dim3(512), 0, stream>>>(part, ST, out);
  k_passN<<<dim3(512), dim3(512), 0, stream>>>(Wp, xp, ST, part);
  k_rs<2><<<dim3(64), dim3(512), 0, stream>>>(part, ST, out);
}